// Round 9
// baseline (294.314 us; speedup 1.0000x reference)
//
#include <hip/hip_runtime.h>
#include <hip/hip_bf16.h>

// Shapes (hardcoded from reference): C=4, B=2, BC=8, HEADS=24, DH=64, D=1536,
// CROSS=2048, S=2048, E=PAD=77. Output f32 [8,2048,1536].

typedef __attribute__((ext_vector_type(8))) short short8;
typedef __attribute__((ext_vector_type(4))) float f32x4;
typedef __attribute__((ext_vector_type(4))) _Float16 half4;

#define DEV __device__ __forceinline__

DEV ushort f2bf(float x) {
  __hip_bfloat16 h = __float2bfloat16(x);
  return *reinterpret_cast<ushort*>(&h);
}

// ---------------- merged conversion kernel (hs + weights + ehs) ----------------

__global__ __launch_bounds__(256) void cvt_all(const float* __restrict__ hs, ushort* __restrict__ hs_bf,
                                               const float* __restrict__ Wq, ushort* __restrict__ Wq_bf,
                                               const float* __restrict__ Wk, ushort* __restrict__ Wk_bf,
                                               const float* __restrict__ Wv, ushort* __restrict__ Wv_bf,
                                               const float* __restrict__ Wo, ushort* __restrict__ Wo_bf,
                                               const float* __restrict__ ehs, ushort* __restrict__ ehs_bf) {
  const int b0 = 6291456;            // hs quads
  const int b1 = b0 + 589824;        // Wq
  const int b2 = b1 + 786432;        // Wk
  const int b3 = b2 + 786432;        // Wv
  const int b4 = b3 + 589824;        // Wo
  const int total = b4 + 327680;     // ehs (640*2048/4)
  int idx = blockIdx.x * blockDim.x + threadIdx.x;
  int stride = gridDim.x * blockDim.x;
  for (int q = idx; q < total; q += stride) {
    const float* in; ushort* out; int qq;
    bool zero = false;
    if (q < b0)      { in = hs;  out = hs_bf;  qq = q; }
    else if (q < b1) { in = Wq;  out = Wq_bf;  qq = q - b0; }
    else if (q < b2) { in = Wk;  out = Wk_bf;  qq = q - b1; }
    else if (q < b3) { in = Wv;  out = Wv_bf;  qq = q - b2; }
    else if (q < b4) { in = Wo;  out = Wo_bf;  qq = q - b3; }
    else {
      qq = q - b4;
      int r = qq >> 9;               // 512 quads per 2048-col row
      in = ehs; out = ehs_bf;
      zero = (r >= 616);
    }
    ushort4 o;
    if (!zero) {
      float4 f = reinterpret_cast<const float4*>(in)[qq];
      o.x = f2bf(f.x); o.y = f2bf(f.y); o.z = f2bf(f.z); o.w = f2bf(f.w);
    } else {
      o.x = 0; o.y = 0; o.z = 0; o.w = 0;
    }
    reinterpret_cast<ushort4*>(out)[qq] = o;
  }
}

// ---------------- deep-pipelined bf16 MFMA GEMM, 128^2 (round-3 proven) ----------
// Used for the K/V projection (M=640).

template <typename OutT>
DEV void gemm_body(const ushort* __restrict__ A, const ushort* __restrict__ B,
                   const float* __restrict__ bias, OutT* __restrict__ C,
                   int M, int N, int K) {
  __shared__ __align__(16) ushort lds[32768];  // 2 bufs x (A 16KB | B 16KB)
  const int tid = threadIdx.x;
  const int lane = tid & 63;
  const int wid = tid >> 6;
  const int wr = wid >> 1, wc = wid & 1;
  const long m0 = (long)blockIdx.x * 128;
  const long n0 = (long)blockIdx.y * 128;
  const int ll = lane & 15, g = lane >> 4;
  const int swz = ll & 7;

  const int srow = wid * 8 + (lane >> 3);
  const int scol = ((lane & 7) ^ (lane >> 3)) * 8;
  const ushort* pa = A + (m0 + srow) * (long)K + scol;
  const ushort* pb = B + (n0 + srow) * (long)K + scol;
  const long qstep = 32 * (long)K;

  f32x4 acc[4][4] = {};

#define STAGE(tt, bsel)                                                                    \
  do {                                                                                     \
    const long kt_ = (long)(tt) * 64;                                                      \
    const int ab_ = (bsel) * 32768 + wid * 1024;                                           \
    _Pragma("unroll") for (int q = 0; q < 4; ++q)                                          \
        __builtin_amdgcn_global_load_lds(                                                  \
            (const __attribute__((address_space(1))) void*)(pa + kt_ + q * qstep),         \
            (__attribute__((address_space(3))) void*)((char*)lds + ab_ + q * 4096),        \
            16, 0, 0);                                                                     \
    _Pragma("unroll") for (int q = 0; q < 4; ++q)                                          \
        __builtin_amdgcn_global_load_lds(                                                  \
            (const __attribute__((address_space(1))) void*)(pb + kt_ + q * qstep),         \
            (__attribute__((address_space(3))) void*)((char*)lds + ab_ + 16384 + q * 4096),\
            16, 0, 0);                                                                     \
  } while (0)

  const int nt = K >> 6;
  STAGE(0, 0);
  STAGE(1, 1);
  asm volatile("s_waitcnt vmcnt(8)" ::: "memory");
  __builtin_amdgcn_s_barrier();

  for (int t = 0; t < nt; ++t) {
    const int buf = t & 1;
    const char* abase = (const char*)lds + buf * 32768;
    const char* bbase = abase + 16384;
    short8 af[4][2], bfr[4][2];
#pragma unroll
    for (int m = 0; m < 4; ++m)
#pragma unroll
      for (int ks = 0; ks < 2; ++ks)
        af[m][ks] = *reinterpret_cast<const short8*>(
            abase + (wr * 64 + m * 16 + ll) * 128 + (((ks * 4 + g) ^ swz) * 16));
#pragma unroll
    for (int n = 0; n < 4; ++n)
#pragma unroll
      for (int ks = 0; ks < 2; ++ks)
        bfr[n][ks] = *reinterpret_cast<const short8*>(
            bbase + (wc * 64 + n * 16 + ll) * 128 + (((ks * 4 + g) ^ swz) * 16));
    asm volatile("s_waitcnt lgkmcnt(0)" ::: "memory");
    __builtin_amdgcn_s_barrier();

    if (t < nt - 2) {
      STAGE(t + 2, buf);
      asm volatile("s_waitcnt vmcnt(8)" ::: "memory");
    } else if (t == nt - 2) {
      asm volatile("s_waitcnt vmcnt(0)" ::: "memory");
    }
    __builtin_amdgcn_sched_barrier(0);
    __builtin_amdgcn_s_setprio(1);
#pragma unroll
    for (int ks = 0; ks < 2; ++ks)
#pragma unroll
      for (int m = 0; m < 4; ++m)
#pragma unroll
        for (int n = 0; n < 4; ++n)
          acc[m][n] =
              __builtin_amdgcn_mfma_f32_16x16x32_bf16(af[m][ks], bfr[n][ks], acc[m][n], 0, 0, 0);
    __builtin_amdgcn_s_setprio(0);
    __builtin_amdgcn_s_barrier();
  }
#undef STAGE

#pragma unroll
  for (int m = 0; m < 4; ++m) {
#pragma unroll
    for (int n = 0; n < 4; ++n) {
      const int row = wr * 64 + m * 16 + g * 4;
      const int col = wc * 64 + n * 16 + ll;
      const float bias_v = bias[n0 + col];
#pragma unroll
      for (int r = 0; r < 4; ++r) {
        float val = acc[m][n][r] + bias_v;
        long off = (m0 + row + r) * (long)N + n0 + col;
        if constexpr (sizeof(OutT) == 2) {
          C[off] = (OutT)f2bf(val);
        } else {
          C[off] = val;
        }
      }
    }
  }
}

// K and V projections fused into one launch (blockIdx.z selects)
__global__ __launch_bounds__(256) void gemm_p_kv(const ushort* __restrict__ A,
                                                 const ushort* __restrict__ Bk,
                                                 const float* __restrict__ bk, float* Ck,
                                                 const ushort* __restrict__ Bv,
                                                 const float* __restrict__ bv, float* Cv,
                                                 int M, int N, int K) {
  if (blockIdx.z == 0)
    gemm_body<float>(A, Bk, bk, Ck, M, N, K);
  else
    gemm_body<float>(A, Bv, bv, Cv, M, N, K);
}

// ---------------- 256x256 4-ring-buffer GEMM (big M/N) ----------------
// 512 threads = 8 waves (2 wr x 4 wc), per-wave output 128x64 -> 2.67 MFMA/KB of
// LDS reads (vs 2.0 for the 128^2 kernel). BK=32; LDS = 4 ring bufs x (A 16KB +
// B 16KB) = 128 KB. ONE barrier + one counted vmcnt per K-tile:
//   top of tile t: vmcnt(8) proves tile t landed (t+1,t+2 = 8 loads in flight);
//   barrier; 12x ds_read(buf t&3); STG(t+3 -> buf (t+3)&3, freed at t-1, its
//   readers lgkm-drained before their tile-t barrier); lgkm(0); 32 MFMA.
// 3-tile stage lead ~600cyc covers HBM latency. 2-bit chunk swizzle
// (chunk^(row&3)) -> exactly 8 lanes/bank-quad on ds_read_b128 = conflict-free.
// Requires M%256==0, N%256==0, K%32==0, K>=128, grid%8==0.

template <typename OutT>
__global__ __launch_bounds__(512, 2) void gemm4b(const ushort* __restrict__ A,
                                                 const ushort* __restrict__ B,
                                                 const float* __restrict__ bias,
                                                 OutT* __restrict__ C,
                                                 int M, int N, int K, int nnx) {
  extern __shared__ char dl[];
  const int tid = threadIdx.x;
  const int lane = tid & 63;
  const int w = tid >> 6;
  const int wr = w >> 2, wc = w & 3;
  const int ll = lane & 15, g = lane >> 4;
  const int swz = ll & 3;

  // bijective XCD swizzle (gridDim.x % 8 == 0), n-fastest decomposition
  const int cpx = gridDim.x >> 3;
  const int sw = (blockIdx.x & 7) * cpx + (blockIdx.x >> 3);
  const long m0 = (long)(sw / nnx) * 256;
  const long n0 = (long)(sw % nnx) * 256;

  // staging: chunk ci = q*512 + tid -> row (tid>>2) + q*128, chunk (tid&3)^(row&3)
  const int srow = tid >> 2;                    // 0..127
  const int scol = ((tid & 3) ^ (srow & 3)) * 8;
  const ushort* pa = A + (m0 + srow) * (long)K + scol;
  const ushort* pb = B + (n0 + srow) * (long)K + scol;
  const long rstep = 128 * (long)K;

  f32x4 acc[8][4] = {};

#define STG(tt)                                                                            \
  do {                                                                                     \
    const long kt_ = (long)(tt) * 32;                                                      \
    char* buf_ = dl + ((tt) & 3) * 32768;                                                  \
    _Pragma("unroll") for (int q = 0; q < 2; ++q) {                                        \
      __builtin_amdgcn_global_load_lds(                                                    \
          (const __attribute__((address_space(1))) void*)(pa + kt_ + q * rstep),           \
          (__attribute__((address_space(3))) void*)(buf_ + q * 8192 + tid * 16),           \
          16, 0, 0);                                                                       \
      __builtin_amdgcn_global_load_lds(                                                    \
          (const __attribute__((address_space(1))) void*)(pb + kt_ + q * rstep),           \
          (__attribute__((address_space(3))) void*)(buf_ + 16384 + q * 8192 + tid * 16),   \
          16, 0, 0);                                                                       \
    }                                                                                      \
  } while (0)

  const int nt = K >> 5;
  STG(0);
  STG(1);
  STG(2);

  for (int t = 0; t < nt; ++t) {
    if (t < nt - 2)
      asm volatile("s_waitcnt vmcnt(8)" ::: "memory");   // tile t landed
    else if (t == nt - 2)
      asm volatile("s_waitcnt vmcnt(4)" ::: "memory");
    else
      asm volatile("s_waitcnt vmcnt(0)" ::: "memory");
    __builtin_amdgcn_s_barrier();   // all waves' tile-t loads landed; buf (t+3)&3 free

    const char* ab = dl + (t & 3) * 32768;
    const char* bb = ab + 16384;
    short8 af[8], bfr[4];
#pragma unroll
    for (int m = 0; m < 8; ++m)
      af[m] = *reinterpret_cast<const short8*>(
          ab + (wr * 128 + m * 16 + ll) * 64 + ((g ^ swz) * 16));
#pragma unroll
    for (int n = 0; n < 4; ++n)
      bfr[n] = *reinterpret_cast<const short8*>(
          bb + (wc * 64 + n * 16 + ll) * 64 + ((g ^ swz) * 16));
    if (t < nt - 3) STG(t + 3);
    asm volatile("s_waitcnt lgkmcnt(0)" ::: "memory");
    __builtin_amdgcn_sched_barrier(0);
    __builtin_amdgcn_s_setprio(1);
#pragma unroll
    for (int m = 0; m < 8; ++m)
#pragma unroll
      for (int n = 0; n < 4; ++n)
        acc[m][n] = __builtin_amdgcn_mfma_f32_16x16x32_bf16(af[m], bfr[n], acc[m][n], 0, 0, 0);
    __builtin_amdgcn_s_setprio(0);
  }
#undef STG

  // epilogue: C/D layout col=lane&15, row=(lane>>4)*4+reg
#pragma unroll
  for (int m = 0; m < 8; ++m) {
#pragma unroll
    for (int n = 0; n < 4; ++n) {
      const int row = wr * 128 + m * 16 + g * 4;
      const int col = wc * 64 + n * 16 + ll;
      const float bias_v = bias[n0 + col];
#pragma unroll
      for (int r = 0; r < 4; ++r) {
        float val = acc[m][n][r] + bias_v;
        long off = (m0 + row + r) * (long)N + n0 + col;
        if constexpr (sizeof(OutT) == 2) {
          C[off] = (OutT)f2bf(val);
        } else {
          C[off] = val;
        }
      }
    }
  }
}

// ---------------- prep: build attn images once ----------------

__global__ __launch_bounds__(256) void prep_kv(const float* __restrict__ k_f,
                                               const float* __restrict__ v_f,
                                               const float* __restrict__ bk,
                                               const float* __restrict__ bv,
                                               ushort* __restrict__ kimg,
                                               ushort* __restrict__ vimg) {
  __shared__ _Float16 vl[80][68];
  const int c = blockIdx.x, h = blockIdx.y, bb = blockIdx.z;
  const int tid = threadIdx.x;
  const long ibase = ((long)(bb * 24 + h)) * 20480 + c * 5120;

  for (int rr = tid; rr < 640; rr += 256) {
    int j = rr >> 3, t = rr & 7;
    short8 v = {};
    const float* src = nullptr;
    if (j < 77)
      src = k_f + ((long)((c * 2 + bb) * 77 + j)) * 1536 + h * 64 + t * 8;
    else if (j == 77)
      src = bk + h * 64 + t * 8;
    if (src) {
      float4 f0 = reinterpret_cast<const float4*>(src)[0];
      float4 f1 = reinterpret_cast<const float4*>(src)[1];
      v[0] = f2bf(f0.x); v[1] = f2bf(f0.y); v[2] = f2bf(f0.z); v[3] = f2bf(f0.w);
      v[4] = f2bf(f1.x); v[5] = f2bf(f1.y); v[6] = f2bf(f1.z); v[7] = f2bf(f1.w);
    }
    *reinterpret_cast<short8*>(kimg + ibase + j * 64 + (t ^ (j & 7)) * 8) = v;
  }
  for (int rr = tid; rr < 640; rr += 256) {
    int j = rr >> 3, t = rr & 7;
    half4 lo = {}, hi = {};
    const float* src = nullptr;
    if (j < 77)
      src = v_f + ((long)((c * 2 + bb) * 77 + j)) * 1536 + h * 64 + t * 8;
    else if (j == 77)
      src = bv + h * 64 + t * 8;
    if (src) {
      float4 f0 = reinterpret_cast<const float4*>(src)[0];
      float4 f1 = reinterpret_cast<const float4*>(src)[1];
      lo[0] = (_Float16)f0.x; lo[1] = (_Float16)f0.y; lo[2] = (_Float16)f0.z; lo[3] = (_Float16)f0.w;
      hi[0] = (_Float16)f1.x; hi[1] = (_Float16)f1.y; hi[2] = (_Float16)f1.z; hi[3] = (_Float16)f1.w;
    }
    *reinterpret_cast<half4*>(&vl[j][t * 8]) = lo;
    *reinterpret_cast<half4*>(&vl[j][t * 8 + 4]) = hi;
  }
  __syncthreads();
  const int d = tid & 63, jg = tid >> 6;
  ushort* vrow = vimg + ibase + d * 80;
  const int x = (d >> 2) & 3;
#pragma unroll
  for (int b = 0; b < 5; ++b) {
    int jb = jg * 5 + b;
    half4 hv;
#pragma unroll
    for (int e = 0; e < 4; ++e) hv[e] = vl[jb * 4 + e][d];
    *reinterpret_cast<half4*>(vrow + ((jb ^ x) << 2)) = hv;
  }
}

// ---------------- MFMA component-softmax attention (v4) ----------------

__global__ __launch_bounds__(256) void attn_v4(const ushort* __restrict__ qg,
                                               const ushort* __restrict__ kimg,
                                               const ushort* __restrict__ vimg,
                                               ushort* __restrict__ ao) {
  __shared__ __align__(16) ushort vt[20480];   // 40 KB (f16 bits)
  const int tid = threadIdx.x;
  const int lane = tid & 63;
  const int w = tid >> 6;
  const int h = blockIdx.y, bb = blockIdx.z;
  const int i0 = blockIdx.x * 64;
  const long ib = ((long)(bb * 24 + h)) * 20480;

#pragma unroll
  for (int p = 0; p < 10; ++p) {
    int is = p * 4 + w;
    __builtin_amdgcn_global_load_lds(
        (const __attribute__((address_space(1))) void*)(vimg + ib + is * 512 + lane * 8),
        (__attribute__((address_space(3))) void*)((char*)vt + is * 1024), 16, 0, 0);
  }

  const int ll = lane & 15, g = lane >> 4;

  f32x4 s[4][5];
#pragma unroll
  for (int c = 0; c < 4; ++c)
#pragma unroll
    for (int m = 0; m < 5; ++m) s[c][m] = (f32x4){0.f, 0.f, 0.f, 0.f};

#pragma unroll
  for (int c = 0; c < 4; ++c) {
    const ushort* qbase =
        qg + ((long)((c * 2 + bb) * 2048 + i0 + w * 16 + ll)) * 1536 + h * 64 + g * 8;
    short8 qf0 = *reinterpret_cast<const short8*>(qbase);
    short8 qf1 = *reinterpret_cast<const short8*>(qbase + 32);
    const ushort* kbase = kimg + ib + c * 5120;
#pragma unroll
    for (int m = 0; m < 5; ++m) {
      const ushort* rb = kbase + (m * 16 + ll) * 64;
      short8 a0 = *reinterpret_cast<const short8*>(rb + (g ^ (ll & 7)) * 8);
      short8 a1 = *reinterpret_cast<const short8*>(rb + ((4 + g) ^ (ll & 7)) * 8);
      s[c][m] = __builtin_amdgcn_mfma_f32_16x16x32_bf16(a0, qf0, s[c][m], 0, 0, 0);
      s[c][m] = __builtin_amdgcn_mfma_f32_16x16x32_bf16(a1, qf1, s[c][m], 0, 0, 0);
    }
  }

  const float scale = 0.125f;
  float wsum0 = 0.f, wsum1 = 0.f, wsum2 = 0.f, wsum3 = 0.f;
#pragma unroll
  for (int m = 0; m < 5; ++m) {
#pragma unroll
    for (int e = 0; e < 4; ++e) {
      float x0 = s[0][m][e] * scale, x1 = s[1][m][e] * scale;
      float x2 = s[2][m][e] * scale, x3 = s[3][m][e] * scale;
      float mx = fmaxf(fmaxf(x0, x1), fmaxf(x2, x3));
      float e0 = __expf(x0 - mx), e1 = __expf(x1 - mx);
      float e2 = __expf(x2 - mx), e3 = __expf(x3 - mx);
      float inv = __fdividef(1.f, e0 + e1 + e2 + e3);
      float w0 = e0 * inv, w1 = e1 * inv, w2 = e2 * inv, w3 = e3 * inv;
      int jj = m * 16 + g * 4 + e;
      float msk = (jj < 77) ? 1.f : 0.f;
      wsum0 += w0 * msk; wsum1 += w1 * msk; wsum2 += w2 * msk; wsum3 += w3 * msk;
      s[0][m][e] = w0; s[1][m][e] = w1; s[2][m][e] = w2; s[3][m][e] = w3;
    }
  }
  wsum0 += __shfl_xor(wsum0, 16); wsum0 += __shfl_xor(wsum0, 32);
  wsum1 += __shfl_xor(wsum1, 16); wsum1 += __shfl_xor(wsum1, 32);
  wsum2 += __shfl_xor(wsum2, 16); wsum2 += __shfl_xor(wsum2, 32);
  wsum3 += __shfl_xor(wsum3, 16); wsum3 += __shfl_xor(wsum3, 32);

  const bool g3 = (g == 3);
  {
    float wsum[4] = {wsum0, wsum1, wsum2, wsum3};
#pragma unroll
    for (int c = 0; c < 4; ++c) {
      float w77 = s[c][4][1];
      float pwv = w77 * (4.0f / 77.0f) * (77.0f - wsum[c]);
      s[c][4][1] = g3 ? pwv : w77;
      s[c][4][2] = g3 ? 0.f : s[c][4][2];
      s[c][4][3] = g3 ? 0.f : s[c][4][3];
    }
  }

  half4 wf[4][5];
#pragma unroll
  for (int c = 0; c < 4; ++c)
#pragma unroll
    for (int m = 0; m < 5; ++m) {
      half4 hv;
      hv[0] = (_Float16)s[c][m][0];
      hv[1] = (_Float16)s[c][m][1];
      hv[2] = (_Float16)s[c][m][2];
      hv[3] = (_Float16)s[c][m][3];
      wf[c][m] = hv;
    }

  __syncthreads();  // V^T staged (drains vmcnt) before PV reads it

  f32x4 o[4][4];
#pragma unroll
  for (int c = 0; c < 4; ++c)
#pragma unroll
    for (int n = 0; n < 4; ++n) o[c][n] = (f32x4){0.f, 0.f, 0.f, 0.f};

#pragma unroll
  for (int c = 0; c < 4; ++c)
#pragma unroll
    for (int m = 0; m < 5; ++m)
#pragma unroll
      for (int n = 0; n < 4; ++n) {
        const int dd = n * 16 + ll;
        const int jb = (m * 4 + g) ^ ((dd >> 2) & 3);
        half4 vf = *reinterpret_cast<const half4*>(
            reinterpret_cast<const _Float16*>(vt) + c * 5120 + dd * 80 + (jb << 2));
        o[c][n] = __builtin_amdgcn_mfma_f32_16x16x16f16(wf[c][m], vf, o[c][n], 0, 0, 0);
      }

#pragma unroll
  for (int c = 0; c < 4; ++c)
#pragma unroll
    for (int n = 0; n < 4; ++n)
#pragma unroll
      for (int r = 0; r < 4; ++r) {
        long row = (long)((c * 2 + bb) * 2048 + i0 + w * 16 + g * 4 + r);
        ao[row * 1536 + h * 64 + n * 16 + ll] = f2bf(o[c][n][r]);
      }
}

// ---------------- launcher ----------------

extern "C" void kernel_launch(void* const* d_in, const int* in_sizes, int n_in,
                              void* d_out, int out_size, void* d_ws, size_t ws_size,
                              hipStream_t stream) {
  (void)in_sizes; (void)n_in; (void)out_size; (void)ws_size;
  const float* hs  = (const float*)d_in[0];
  const float* ehs = (const float*)d_in[1];
  const float* Wq  = (const float*)d_in[2];
  const float* bq  = (const float*)d_in[3];
  const float* Wk  = (const float*)d_in[4];
  const float* bk  = (const float*)d_in[5];
  const float* Wv  = (const float*)d_in[6];
  const float* bv  = (const float*)d_in[7];
  const float* Wo  = (const float*)d_in[8];
  const float* bo  = (const float*)d_in[9];
  float* out = (float*)d_out;

  char* ws = (char*)d_ws;
  size_t off = 0;
  auto alloc = [&](size_t bytes) {
    char* p = ws + off;
    off += (bytes + 255) & ~(size_t)255;
    return p;
  };
  ushort* hs_bf  = (ushort*)alloc(16384UL * 1536 * 2);
  ushort* ehs_bf = (ushort*)alloc(640UL * 2048 * 2);
  ushort* Wq_bf  = (ushort*)alloc(1536UL * 1536 * 2);
  ushort* Wk_bf  = (ushort*)alloc(1536UL * 2048 * 2);
  ushort* Wv_bf  = (ushort*)alloc(1536UL * 2048 * 2);
  ushort* Wo_bf  = (ushort*)alloc(1536UL * 1536 * 2);
  ushort* q_bf   = (ushort*)alloc(16384UL * 1536 * 2);
  float*  k_f    = (float*)alloc(640UL * 1536 * 4);
  float*  v_f    = (float*)alloc(640UL * 1536 * 4);
  ushort* ao_bf  = (ushort*)alloc(16384UL * 1536 * 2);
  ushort* kimg   = (ushort*)alloc(48UL * 20480 * 2);
  ushort* vimg   = (ushort*)alloc(48UL * 20480 * 2);

  // allow 128 KB dynamic LDS (deterministic, called every launch)
  hipFuncSetAttribute(reinterpret_cast<const void*>(&gemm4b<ushort>),
                      hipFuncAttributeMaxDynamicSharedMemorySize, 131072);
  hipFuncSetAttribute(reinterpret_cast<const void*>(&gemm4b<float>),
                      hipFuncAttributeMaxDynamicSharedMemorySize, 131072);

  dim3 b256(256);
  cvt_all<<<4096, b256, 0, stream>>>(hs, hs_bf, Wq, Wq_bf, Wk, Wk_bf, Wv, Wv_bf,
                                     Wo, Wo_bf, ehs, ehs_bf);

  // K,V projections fused (M padded to 640; rows 616..639 bias-only, unused)
  gemm_p_kv<<<dim3(5, 12, 2), b256, 0, stream>>>(ehs_bf, Wk_bf, bk, k_f, Wv_bf, bv, v_f,
                                                 640, 1536, 2048);
  // build attn images
  prep_kv<<<dim3(4, 24, 2), b256, 0, stream>>>(k_f, v_f, bk, bv, kimg, vimg);
  // Q projection (256^2 4-ring kernel, 384 blocks)
  gemm4b<ushort><<<384, 512, 131072, stream>>>(hs_bf, Wq_bf, bq, q_bf, 16384, 1536, 1536, 6);
  // MFMA component-softmax attention
  attn_v4<<<dim3(32, 24, 2), b256, 0, stream>>>(q_bf, kimg, vimg, ao_bf);
  // output projection -> d_out (f32)
  gemm4b<float><<<384, 512, 131072, stream>>>(ao_bf, Wo_bf, bo, out, 16384, 1536, 1536, 6);
}

// Round 10
// 289.287 us; speedup vs baseline: 1.0174x; 1.0174x over previous
//
#include <hip/hip_runtime.h>
#include <hip/hip_bf16.h>

// Shapes (hardcoded from reference): C=4, B=2, BC=8, HEADS=24, DH=64, D=1536,
// CROSS=2048, S=2048, E=PAD=77. Output f32 [8,2048,1536].

typedef __attribute__((ext_vector_type(8))) short short8;
typedef __attribute__((ext_vector_type(4))) float f32x4;
typedef __attribute__((ext_vector_type(4))) _Float16 half4;

#define DEV __device__ __forceinline__

DEV ushort f2bf(float x) {
  __hip_bfloat16 h = __float2bfloat16(x);
  return *reinterpret_cast<ushort*>(&h);
}

// ---------------- merged conversion kernel (hs + weights + ehs) ----------------

__global__ __launch_bounds__(256) void cvt_all(const float* __restrict__ hs, ushort* __restrict__ hs_bf,
                                               const float* __restrict__ Wq, ushort* __restrict__ Wq_bf,
                                               const float* __restrict__ Wk, ushort* __restrict__ Wk_bf,
                                               const float* __restrict__ Wv, ushort* __restrict__ Wv_bf,
                                               const float* __restrict__ Wo, ushort* __restrict__ Wo_bf,
                                               const float* __restrict__ ehs, ushort* __restrict__ ehs_bf) {
  const int b0 = 6291456;            // hs quads
  const int b1 = b0 + 589824;        // Wq
  const int b2 = b1 + 786432;        // Wk
  const int b3 = b2 + 786432;        // Wv
  const int b4 = b3 + 589824;        // Wo
  const int total = b4 + 327680;     // ehs (640*2048/4)
  int idx = blockIdx.x * blockDim.x + threadIdx.x;
  int stride = gridDim.x * blockDim.x;
  for (int q = idx; q < total; q += stride) {
    const float* in; ushort* out; int qq;
    bool zero = false;
    if (q < b0)      { in = hs;  out = hs_bf;  qq = q; }
    else if (q < b1) { in = Wq;  out = Wq_bf;  qq = q - b0; }
    else if (q < b2) { in = Wk;  out = Wk_bf;  qq = q - b1; }
    else if (q < b3) { in = Wv;  out = Wv_bf;  qq = q - b2; }
    else if (q < b4) { in = Wo;  out = Wo_bf;  qq = q - b3; }
    else {
      qq = q - b4;
      int r = qq >> 9;               // 512 quads per 2048-col row
      in = ehs; out = ehs_bf;
      zero = (r >= 616);
    }
    ushort4 o;
    if (!zero) {
      float4 f = reinterpret_cast<const float4*>(in)[qq];
      o.x = f2bf(f.x); o.y = f2bf(f.y); o.z = f2bf(f.z); o.w = f2bf(f.w);
    } else {
      o.x = 0; o.y = 0; o.z = 0; o.w = 0;
    }
    reinterpret_cast<ushort4*>(out)[qq] = o;
  }
}

// ---------------- deep-pipelined bf16 MFMA GEMM, 128^2 (round-3 proven) ----------

template <typename OutT>
DEV void gemm_body(const ushort* __restrict__ A, const ushort* __restrict__ B,
                   const float* __restrict__ bias, OutT* __restrict__ C,
                   int M, int N, int K) {
  __shared__ __align__(16) ushort lds[32768];  // 2 bufs x (A 16KB | B 16KB)
  const int tid = threadIdx.x;
  const int lane = tid & 63;
  const int wid = tid >> 6;
  const int wr = wid >> 1, wc = wid & 1;
  const long m0 = (long)blockIdx.x * 128;
  const long n0 = (long)blockIdx.y * 128;
  const int ll = lane & 15, g = lane >> 4;
  const int swz = ll & 7;

  const int srow = wid * 8 + (lane >> 3);
  const int scol = ((lane & 7) ^ (lane >> 3)) * 8;
  const ushort* pa = A + (m0 + srow) * (long)K + scol;
  const ushort* pb = B + (n0 + srow) * (long)K + scol;
  const long qstep = 32 * (long)K;

  f32x4 acc[4][4] = {};

#define STAGE(tt, bsel)                                                                    \
  do {                                                                                     \
    const long kt_ = (long)(tt) * 64;                                                      \
    const int ab_ = (bsel) * 32768 + wid * 1024;                                           \
    _Pragma("unroll") for (int q = 0; q < 4; ++q)                                          \
        __builtin_amdgcn_global_load_lds(                                                  \
            (const __attribute__((address_space(1))) void*)(pa + kt_ + q * qstep),         \
            (__attribute__((address_space(3))) void*)((char*)lds + ab_ + q * 4096),        \
            16, 0, 0);                                                                     \
    _Pragma("unroll") for (int q = 0; q < 4; ++q)                                          \
        __builtin_amdgcn_global_load_lds(                                                  \
            (const __attribute__((address_space(1))) void*)(pb + kt_ + q * qstep),         \
            (__attribute__((address_space(3))) void*)((char*)lds + ab_ + 16384 + q * 4096),\
            16, 0, 0);                                                                     \
  } while (0)

  const int nt = K >> 6;
  STAGE(0, 0);
  STAGE(1, 1);
  asm volatile("s_waitcnt vmcnt(8)" ::: "memory");
  __builtin_amdgcn_s_barrier();

  for (int t = 0; t < nt; ++t) {
    const int buf = t & 1;
    const char* abase = (const char*)lds + buf * 32768;
    const char* bbase = abase + 16384;
    short8 af[4][2], bfr[4][2];
#pragma unroll
    for (int m = 0; m < 4; ++m)
#pragma unroll
      for (int ks = 0; ks < 2; ++ks)
        af[m][ks] = *reinterpret_cast<const short8*>(
            abase + (wr * 64 + m * 16 + ll) * 128 + (((ks * 4 + g) ^ swz) * 16));
#pragma unroll
    for (int n = 0; n < 4; ++n)
#pragma unroll
      for (int ks = 0; ks < 2; ++ks)
        bfr[n][ks] = *reinterpret_cast<const short8*>(
            bbase + (wc * 64 + n * 16 + ll) * 128 + (((ks * 4 + g) ^ swz) * 16));
    asm volatile("s_waitcnt lgkmcnt(0)" ::: "memory");
    __builtin_amdgcn_s_barrier();

    if (t < nt - 2) {
      STAGE(t + 2, buf);
      asm volatile("s_waitcnt vmcnt(8)" ::: "memory");
    } else if (t == nt - 2) {
      asm volatile("s_waitcnt vmcnt(0)" ::: "memory");
    }
    __builtin_amdgcn_sched_barrier(0);
    __builtin_amdgcn_s_setprio(1);
#pragma unroll
    for (int ks = 0; ks < 2; ++ks)
#pragma unroll
      for (int m = 0; m < 4; ++m)
#pragma unroll
        for (int n = 0; n < 4; ++n)
          acc[m][n] =
              __builtin_amdgcn_mfma_f32_16x16x32_bf16(af[m][ks], bfr[n][ks], acc[m][n], 0, 0, 0);
    __builtin_amdgcn_s_setprio(0);
    __builtin_amdgcn_s_barrier();
  }
#undef STAGE

#pragma unroll
  for (int m = 0; m < 4; ++m) {
#pragma unroll
    for (int n = 0; n < 4; ++n) {
      const int row = wr * 64 + m * 16 + g * 4;
      const int col = wc * 64 + n * 16 + ll;
      const float bias_v = bias[n0 + col];
#pragma unroll
      for (int r = 0; r < 4; ++r) {
        float val = acc[m][n][r] + bias_v;
        long off = (m0 + row + r) * (long)N + n0 + col;
        if constexpr (sizeof(OutT) == 2) {
          C[off] = (OutT)f2bf(val);
        } else {
          C[off] = val;
        }
      }
    }
  }
}

template <typename OutT>
__global__ __launch_bounds__(256) void gemm_p(const ushort* __restrict__ A,
                                              const ushort* __restrict__ B,
                                              const float* __restrict__ bias,
                                              OutT* __restrict__ C, int M, int N, int K) {
  gemm_body<OutT>(A, B, bias, C, M, N, K);
}

// K and V projections fused into one launch (blockIdx.z selects)
__global__ __launch_bounds__(256) void gemm_p_kv(const ushort* __restrict__ A,
                                                 const ushort* __restrict__ Bk,
                                                 const float* __restrict__ bk, float* Ck,
                                                 const ushort* __restrict__ Bv,
                                                 const float* __restrict__ bv, float* Cv,
                                                 int M, int N, int K) {
  if (blockIdx.z == 0)
    gemm_body<float>(A, Bk, bk, Ck, M, N, K);
  else
    gemm_body<float>(A, Bv, bv, Cv, M, N, K);
}

// ---------------- 128^2 4-buffer-ring GEMM (A/B test vs gemm_p) ----------------
// Same tile/wave/frag/epilogue as gemm_p, but BK=32 and a 4-deep LDS ring
// (4 x 16KB = 64KB -> still 2 blocks/CU). ONE barrier + ONE counted vmcnt per
// K-tile (vs 3 barriers per 64-K in gemm_p):
//   top of t: vmcnt(8) [own tile-t loads landed; t+1,t+2 in flight = 8/thread],
//   barrier [all waves' t landed; also: all waves finished reading t-1],
//   8x ds_read(buf t&3), STG(t+3 -> buf (t-1)&3, read-drained), lgkm(0), 16 MFMA.
// Conflict-free swizzle for 64B rows (16-lane granularity, 2 lanes/start-bank):
//   read chunk = g ^ ((ll>>1)&3); staging source chunk = (tid&3) ^ ((tid>>3)&3).
// Requires M%128==0, N%128==0, K%32==0, K>=128.

template <typename OutT>
__global__ __launch_bounds__(256) void gemm_r(const ushort* __restrict__ A,
                                              const ushort* __restrict__ B,
                                              const float* __restrict__ bias,
                                              OutT* __restrict__ C, int M, int N, int K) {
  __shared__ __align__(16) ushort lds[32768];  // 4 bufs x (A 8KB | B 8KB)
  const int tid = threadIdx.x;
  const int lane = tid & 63;
  const int wid = tid >> 6;
  const int wr = wid >> 1, wc = wid & 1;
  const long m0 = (long)blockIdx.x * 128;
  const long n0 = (long)blockIdx.y * 128;
  const int ll = lane & 15, g = lane >> 4;
  const int swz = (ll >> 1) & 3;

  // staging: chunk ci = q*256 + tid -> row q*64 + (tid>>2), chunk (tid&3)^((tid>>3)&3)
  const int srow = tid >> 2;                          // 0..63
  const int scol = ((tid & 3) ^ ((tid >> 3) & 3)) * 8;
  const ushort* pa = A + (m0 + srow) * (long)K + scol;
  const ushort* pb = B + (n0 + srow) * (long)K + scol;
  const long rstep = 64 * (long)K;

  f32x4 acc[4][4] = {};

#define STG(tt)                                                                            \
  do {                                                                                     \
    const long kt_ = (long)(tt) * 32;                                                      \
    char* buf_ = (char*)lds + ((tt) & 3) * 16384;                                          \
    _Pragma("unroll") for (int q = 0; q < 2; ++q) {                                        \
      __builtin_amdgcn_global_load_lds(                                                    \
          (const __attribute__((address_space(1))) void*)(pa + kt_ + q * rstep),           \
          (__attribute__((address_space(3))) void*)(buf_ + q * 4096 + tid * 16),           \
          16, 0, 0);                                                                       \
      __builtin_amdgcn_global_load_lds(                                                    \
          (const __attribute__((address_space(1))) void*)(pb + kt_ + q * rstep),           \
          (__attribute__((address_space(3))) void*)(buf_ + 8192 + q * 4096 + tid * 16),    \
          16, 0, 0);                                                                       \
    }                                                                                      \
  } while (0)

  const int nt = K >> 5;
  STG(0);
  STG(1);
  STG(2);

  for (int t = 0; t < nt; ++t) {
    if (t < nt - 2)
      asm volatile("s_waitcnt vmcnt(8)" ::: "memory");   // tile t landed (mine)
    else if (t == nt - 2)
      asm volatile("s_waitcnt vmcnt(4)" ::: "memory");
    else
      asm volatile("s_waitcnt vmcnt(0)" ::: "memory");
    __builtin_amdgcn_s_barrier();  // ALL waves: tile t landed AND tile t-1 reads drained

    const char* ab = (const char*)lds + (t & 3) * 16384;
    const char* bb = ab + 8192;
    short8 af[4], bfr[4];
#pragma unroll
    for (int m = 0; m < 4; ++m)
      af[m] = *reinterpret_cast<const short8*>(
          ab + (wr * 64 + m * 16 + ll) * 64 + ((g ^ swz) * 16));
#pragma unroll
    for (int n = 0; n < 4; ++n)
      bfr[n] = *reinterpret_cast<const short8*>(
          bb + (wc * 64 + n * 16 + ll) * 64 + ((g ^ swz) * 16));
    if (t < nt - 3) STG(t + 3);   // overwrites buf (t-1)&3 (read-drained above)
    asm volatile("s_waitcnt lgkmcnt(0)" ::: "memory");
    __builtin_amdgcn_sched_barrier(0);
    __builtin_amdgcn_s_setprio(1);
#pragma unroll
    for (int m = 0; m < 4; ++m)
#pragma unroll
      for (int n = 0; n < 4; ++n)
        acc[m][n] = __builtin_amdgcn_mfma_f32_16x16x32_bf16(af[m], bfr[n], acc[m][n], 0, 0, 0);
    __builtin_amdgcn_s_setprio(0);
  }
#undef STG

  // epilogue: C/D layout col=lane&15, row=(lane>>4)*4+reg
#pragma unroll
  for (int m = 0; m < 4; ++m) {
#pragma unroll
    for (int n = 0; n < 4; ++n) {
      const int row = wr * 64 + m * 16 + g * 4;
      const int col = wc * 64 + n * 16 + ll;
      const float bias_v = bias[n0 + col];
#pragma unroll
      for (int r = 0; r < 4; ++r) {
        float val = acc[m][n][r] + bias_v;
        long off = (m0 + row + r) * (long)N + n0 + col;
        if constexpr (sizeof(OutT) == 2) {
          C[off] = (OutT)f2bf(val);
        } else {
          C[off] = val;
        }
      }
    }
  }
}

// ---------------- prep: build attn images once ----------------

__global__ __launch_bounds__(256) void prep_kv(const float* __restrict__ k_f,
                                               const float* __restrict__ v_f,
                                               const float* __restrict__ bk,
                                               const float* __restrict__ bv,
                                               ushort* __restrict__ kimg,
                                               ushort* __restrict__ vimg) {
  __shared__ _Float16 vl[80][68];
  const int c = blockIdx.x, h = blockIdx.y, bb = blockIdx.z;
  const int tid = threadIdx.x;
  const long ibase = ((long)(bb * 24 + h)) * 20480 + c * 5120;

  for (int rr = tid; rr < 640; rr += 256) {
    int j = rr >> 3, t = rr & 7;
    short8 v = {};
    const float* src = nullptr;
    if (j < 77)
      src = k_f + ((long)((c * 2 + bb) * 77 + j)) * 1536 + h * 64 + t * 8;
    else if (j == 77)
      src = bk + h * 64 + t * 8;
    if (src) {
      float4 f0 = reinterpret_cast<const float4*>(src)[0];
      float4 f1 = reinterpret_cast<const float4*>(src)[1];
      v[0] = f2bf(f0.x); v[1] = f2bf(f0.y); v[2] = f2bf(f0.z); v[3] = f2bf(f0.w);
      v[4] = f2bf(f1.x); v[5] = f2bf(f1.y); v[6] = f2bf(f1.z); v[7] = f2bf(f1.w);
    }
    *reinterpret_cast<short8*>(kimg + ibase + j * 64 + (t ^ (j & 7)) * 8) = v;
  }
  for (int rr = tid; rr < 640; rr += 256) {
    int j = rr >> 3, t = rr & 7;
    half4 lo = {}, hi = {};
    const float* src = nullptr;
    if (j < 77)
      src = v_f + ((long)((c * 2 + bb) * 77 + j)) * 1536 + h * 64 + t * 8;
    else if (j == 77)
      src = bv + h * 64 + t * 8;
    if (src) {
      float4 f0 = reinterpret_cast<const float4*>(src)[0];
      float4 f1 = reinterpret_cast<const float4*>(src)[1];
      lo[0] = (_Float16)f0.x; lo[1] = (_Float16)f0.y; lo[2] = (_Float16)f0.z; lo[3] = (_Float16)f0.w;
      hi[0] = (_Float16)f1.x; hi[1] = (_Float16)f1.y; hi[2] = (_Float16)f1.z; hi[3] = (_Float16)f1.w;
    }
    *reinterpret_cast<half4*>(&vl[j][t * 8]) = lo;
    *reinterpret_cast<half4*>(&vl[j][t * 8 + 4]) = hi;
  }
  __syncthreads();
  const int d = tid & 63, jg = tid >> 6;
  ushort* vrow = vimg + ibase + d * 80;
  const int x = (d >> 2) & 3;
#pragma unroll
  for (int b = 0; b < 5; ++b) {
    int jb = jg * 5 + b;
    half4 hv;
#pragma unroll
    for (int e = 0; e < 4; ++e) hv[e] = vl[jb * 4 + e][d];
    *reinterpret_cast<half4*>(vrow + ((jb ^ x) << 2)) = hv;
  }
}

// ---------------- MFMA component-softmax attention (v4) ----------------

__global__ __launch_bounds__(256) void attn_v4(const ushort* __restrict__ qg,
                                               const ushort* __restrict__ kimg,
                                               const ushort* __restrict__ vimg,
                                               ushort* __restrict__ ao) {
  __shared__ __align__(16) ushort vt[20480];   // 40 KB (f16 bits)
  const int tid = threadIdx.x;
  const int lane = tid & 63;
  const int w = tid >> 6;
  const int h = blockIdx.y, bb = blockIdx.z;
  const int i0 = blockIdx.x * 64;
  const long ib = ((long)(bb * 24 + h)) * 20480;

#pragma unroll
  for (int p = 0; p < 10; ++p) {
    int is = p * 4 + w;
    __builtin_amdgcn_global_load_lds(
        (const __attribute__((address_space(1))) void*)(vimg + ib + is * 512 + lane * 8),
        (__attribute__((address_space(3))) void*)((char*)vt + is * 1024), 16, 0, 0);
  }

  const int ll = lane & 15, g = lane >> 4;

  f32x4 s[4][5];
#pragma unroll
  for (int c = 0; c < 4; ++c)
#pragma unroll
    for (int m = 0; m < 5; ++m) s[c][m] = (f32x4){0.f, 0.f, 0.f, 0.f};

#pragma unroll
  for (int c = 0; c < 4; ++c) {
    const ushort* qbase =
        qg + ((long)((c * 2 + bb) * 2048 + i0 + w * 16 + ll)) * 1536 + h * 64 + g * 8;
    short8 qf0 = *reinterpret_cast<const short8*>(qbase);
    short8 qf1 = *reinterpret_cast<const short8*>(qbase + 32);
    const ushort* kbase = kimg + ib + c * 5120;
#pragma unroll
    for (int m = 0; m < 5; ++m) {
      const ushort* rb = kbase + (m * 16 + ll) * 64;
      short8 a0 = *reinterpret_cast<const short8*>(rb + (g ^ (ll & 7)) * 8);
      short8 a1 = *reinterpret_cast<const short8*>(rb + ((4 + g) ^ (ll & 7)) * 8);
      s[c][m] = __builtin_amdgcn_mfma_f32_16x16x32_bf16(a0, qf0, s[c][m], 0, 0, 0);
      s[c][m] = __builtin_amdgcn_mfma_f32_16x16x32_bf16(a1, qf1, s[c][m], 0, 0, 0);
    }
  }

  const float scale = 0.125f;
  float wsum0 = 0.f, wsum1 = 0.f, wsum2 = 0.f, wsum3 = 0.f;
#pragma unroll
  for (int m = 0; m < 5; ++m) {
#pragma unroll
    for (int e = 0; e < 4; ++e) {
      float x0 = s[0][m][e] * scale, x1 = s[1][m][e] * scale;
      float x2 = s[2][m][e] * scale, x3 = s[3][m][e] * scale;
      float mx = fmaxf(fmaxf(x0, x1), fmaxf(x2, x3));
      float e0 = __expf(x0 - mx), e1 = __expf(x1 - mx);
      float e2 = __expf(x2 - mx), e3 = __expf(x3 - mx);
      float inv = __fdividef(1.f, e0 + e1 + e2 + e3);
      float w0 = e0 * inv, w1 = e1 * inv, w2 = e2 * inv, w3 = e3 * inv;
      int jj = m * 16 + g * 4 + e;
      float msk = (jj < 77) ? 1.f : 0.f;
      wsum0 += w0 * msk; wsum1 += w1 * msk; wsum2 += w2 * msk; wsum3 += w3 * msk;
      s[0][m][e] = w0; s[1][m][e] = w1; s[2][m][e] = w2; s[3][m][e] = w3;
    }
  }
  wsum0 += __shfl_xor(wsum0, 16); wsum0 += __shfl_xor(wsum0, 32);
  wsum1 += __shfl_xor(wsum1, 16); wsum1 += __shfl_xor(wsum1, 32);
  wsum2 += __shfl_xor(wsum2, 16); wsum2 += __shfl_xor(wsum2, 32);
  wsum3 += __shfl_xor(wsum3, 16); wsum3 += __shfl_xor(wsum3, 32);

  const bool g3 = (g == 3);
  {
    float wsum[4] = {wsum0, wsum1, wsum2, wsum3};
#pragma unroll
    for (int c = 0; c < 4; ++c) {
      float w77 = s[c][4][1];
      float pwv = w77 * (4.0f / 77.0f) * (77.0f - wsum[c]);
      s[c][4][1] = g3 ? pwv : w77;
      s[c][4][2] = g3 ? 0.f : s[c][4][2];
      s[c][4][3] = g3 ? 0.f : s[c][4][3];
    }
  }

  half4 wf[4][5];
#pragma unroll
  for (int c = 0; c < 4; ++c)
#pragma unroll
    for (int m = 0; m < 5; ++m) {
      half4 hv;
      hv[0] = (_Float16)s[c][m][0];
      hv[1] = (_Float16)s[c][m][1];
      hv[2] = (_Float16)s[c][m][2];
      hv[3] = (_Float16)s[c][m][3];
      wf[c][m] = hv;
    }

  __syncthreads();  // V^T staged (drains vmcnt) before PV reads it

  f32x4 o[4][4];
#pragma unroll
  for (int c = 0; c < 4; ++c)
#pragma unroll
    for (int n = 0; n < 4; ++n) o[c][n] = (f32x4){0.f, 0.f, 0.f, 0.f};

#pragma unroll
  for (int c = 0; c < 4; ++c)
#pragma unroll
    for (int m = 0; m < 5; ++m)
#pragma unroll
      for (int n = 0; n < 4; ++n) {
        const int dd = n * 16 + ll;
        const int jb = (m * 4 + g) ^ ((dd >> 2) & 3);
        half4 vf = *reinterpret_cast<const half4*>(
            reinterpret_cast<const _Float16*>(vt) + c * 5120 + dd * 80 + (jb << 2));
        o[c][n] = __builtin_amdgcn_mfma_f32_16x16x16f16(wf[c][m], vf, o[c][n], 0, 0, 0);
      }

#pragma unroll
  for (int c = 0; c < 4; ++c)
#pragma unroll
    for (int n = 0; n < 4; ++n)
#pragma unroll
      for (int r = 0; r < 4; ++r) {
        long row = (long)((c * 2 + bb) * 2048 + i0 + w * 16 + g * 4 + r);
        ao[row * 1536 + h * 64 + n * 16 + ll] = f2bf(o[c][n][r]);
      }
}

// ---------------- launcher ----------------

extern "C" void kernel_launch(void* const* d_in, const int* in_sizes, int n_in,
                              void* d_out, int out_size, void* d_ws, size_t ws_size,
                              hipStream_t stream) {
  (void)in_sizes; (void)n_in; (void)out_size; (void)ws_size;
  const float* hs  = (const float*)d_in[0];
  const float* ehs = (const float*)d_in[1];
  const float* Wq  = (const float*)d_in[2];
  const float* bq  = (const float*)d_in[3];
  const float* Wk  = (const float*)d_in[4];
  const float* bk  = (const float*)d_in[5];
  const float* Wv  = (const float*)d_in[6];
  const float* bv  = (const float*)d_in[7];
  const float* Wo  = (const float*)d_in[8];
  const float* bo  = (const float*)d_in[9];
  float* out = (float*)d_out;

  char* ws = (char*)d_ws;
  size_t off = 0;
  auto alloc = [&](size_t bytes) {
    char* p = ws + off;
    off += (bytes + 255) & ~(size_t)255;
    return p;
  };
  ushort* hs_bf  = (ushort*)alloc(16384UL * 1536 * 2);
  ushort* ehs_bf = (ushort*)alloc(640UL * 2048 * 2);
  ushort* Wq_bf  = (ushort*)alloc(1536UL * 1536 * 2);
  ushort* Wk_bf  = (ushort*)alloc(1536UL * 2048 * 2);
  ushort* Wv_bf  = (ushort*)alloc(1536UL * 2048 * 2);
  ushort* Wo_bf  = (ushort*)alloc(1536UL * 1536 * 2);
  ushort* q_bf   = (ushort*)alloc(16384UL * 1536 * 2);
  float*  k_f    = (float*)alloc(640UL * 1536 * 4);
  float*  v_f    = (float*)alloc(640UL * 1536 * 4);
  ushort* ao_bf  = (ushort*)alloc(16384UL * 1536 * 2);
  ushort* kimg   = (ushort*)alloc(48UL * 20480 * 2);
  ushort* vimg   = (ushort*)alloc(48UL * 20480 * 2);

  dim3 b256(256);
  cvt_all<<<4096, b256, 0, stream>>>(hs, hs_bf, Wq, Wq_bf, Wk, Wk_bf, Wv, Wv_bf,
                                     Wo, Wo_bf, ehs, ehs_bf);

  // K,V projections fused (M padded to 640; rows 616..639 bias-only, unused)
  gemm_p_kv<<<dim3(5, 12, 2), b256, 0, stream>>>(ehs_bf, Wk_bf, bk, k_f, Wv_bf, bv, v_f,
                                                 640, 1536, 2048);
  // build attn images
  prep_kv<<<dim3(4, 24, 2), b256, 0, stream>>>(k_f, v_f, bk, bv, kimg, vimg);
  // Q projection: 4-buffer-ring variant (A/B test vs gemm_p)
  gemm_r<ushort><<<dim3(128, 12), b256, 0, stream>>>(hs_bf, Wq_bf, bq, q_bf, 16384, 1536, 1536);
  // MFMA component-softmax attention
  attn_v4<<<dim3(32, 24, 2), b256, 0, stream>>>(q_bf, kimg, vimg, ao_bf);
  // output projection -> d_out (f32): proven 2-phase kernel
  gemm_p<float><<<dim3(128, 12), b256, 0, stream>>>(ao_bf, Wo_bf, bo, out, 16384, 1536, 1536);
}

// Round 11
// 270.130 us; speedup vs baseline: 1.0895x; 1.0709x over previous
//
#include <hip/hip_runtime.h>
#include <hip/hip_bf16.h>

// Shapes (hardcoded from reference): C=4, B=2, BC=8, HEADS=24, DH=64, D=1536,
// CROSS=2048, S=2048, E=PAD=77. Output f32 [8,2048,1536].

typedef __attribute__((ext_vector_type(8))) short short8;
typedef __attribute__((ext_vector_type(4))) float f32x4;
typedef __attribute__((ext_vector_type(4))) _Float16 half4;

#define DEV __device__ __forceinline__

DEV ushort f2bf(float x) {
  __hip_bfloat16 h = __float2bfloat16(x);
  return *reinterpret_cast<ushort*>(&h);
}

// ---------------- merged conversion kernel (weights + ehs; hs handled here too) ----

__global__ __launch_bounds__(256) void cvt_all(const float* __restrict__ hs, ushort* __restrict__ hs_bf,
                                               const float* __restrict__ Wq, ushort* __restrict__ Wq_bf,
                                               const float* __restrict__ Wk, ushort* __restrict__ Wk_bf,
                                               const float* __restrict__ Wv, ushort* __restrict__ Wv_bf,
                                               const float* __restrict__ Wo, ushort* __restrict__ Wo_bf,
                                               const float* __restrict__ ehs, ushort* __restrict__ ehs_bf) {
  const int b0 = 6291456;            // hs quads
  const int b1 = b0 + 589824;        // Wq
  const int b2 = b1 + 786432;        // Wk
  const int b3 = b2 + 786432;        // Wv
  const int b4 = b3 + 589824;        // Wo
  const int total = b4 + 327680;     // ehs (640*2048/4)
  int idx = blockIdx.x * blockDim.x + threadIdx.x;
  int stride = gridDim.x * blockDim.x;
  for (int q = idx; q < total; q += stride) {
    const float* in; ushort* out; int qq;
    bool zero = false;
    if (q < b0)      { in = hs;  out = hs_bf;  qq = q; }
    else if (q < b1) { in = Wq;  out = Wq_bf;  qq = q - b0; }
    else if (q < b2) { in = Wk;  out = Wk_bf;  qq = q - b1; }
    else if (q < b3) { in = Wv;  out = Wv_bf;  qq = q - b2; }
    else if (q < b4) { in = Wo;  out = Wo_bf;  qq = q - b3; }
    else {
      qq = q - b4;
      int r = qq >> 9;               // 512 quads per 2048-col row
      in = ehs; out = ehs_bf;
      zero = (r >= 616);
    }
    ushort4 o;
    if (!zero) {
      float4 f = reinterpret_cast<const float4*>(in)[qq];
      o.x = f2bf(f.x); o.y = f2bf(f.y); o.z = f2bf(f.z); o.w = f2bf(f.w);
    } else {
      o.x = 0; o.y = 0; o.z = 0; o.w = 0;
    }
    reinterpret_cast<ushort4*>(out)[qq] = o;
  }
}

// ---------------- deep-pipelined bf16 MFMA GEMM, 128^2 (round-3 proven) ----------
// C[m][n] = sum_k A[m][k]*B[n][k] + bias[n].  128x128 tile, BK=64, 4 waves (2x2).
// Double-buffered LDS (64 KB -> 2 blocks/CU). Raw s_barrier + counted vmcnt:
// stage tile t+2 while computing t; vmcnt(8) keeps 8 loads in flight across
// barriers (never drains to 0 in the main loop). T2 swizzle: global source
// chunk pre-swizzled (chunk ^ (row&7)), LDS linear, reads apply same XOR.
// A/B-validated best vs: B-from-L2 (r4), 256^2 coarse (r6), fused-cvt (r8),
// BK=32 256^2 (r9), BK=32 4-ring (r10) -- all regressed.

template <typename OutT>
DEV void gemm_body(const ushort* __restrict__ A, const ushort* __restrict__ B,
                   const float* __restrict__ bias, OutT* __restrict__ C,
                   int M, int N, int K) {
  __shared__ __align__(16) ushort lds[32768];  // 2 bufs x (A 16KB | B 16KB)
  const int tid = threadIdx.x;
  const int lane = tid & 63;
  const int wid = tid >> 6;
  const int wr = wid >> 1, wc = wid & 1;
  const long m0 = (long)blockIdx.x * 128;
  const long n0 = (long)blockIdx.y * 128;
  const int ll = lane & 15, g = lane >> 4;
  const int swz = ll & 7;

  const int srow = wid * 8 + (lane >> 3);
  const int scol = ((lane & 7) ^ (lane >> 3)) * 8;
  const ushort* pa = A + (m0 + srow) * (long)K + scol;
  const ushort* pb = B + (n0 + srow) * (long)K + scol;
  const long qstep = 32 * (long)K;

  f32x4 acc[4][4] = {};

#define STAGE(tt, bsel)                                                                    \
  do {                                                                                     \
    const long kt_ = (long)(tt) * 64;                                                      \
    const int ab_ = (bsel) * 32768 + wid * 1024;                                           \
    _Pragma("unroll") for (int q = 0; q < 4; ++q)                                          \
        __builtin_amdgcn_global_load_lds(                                                  \
            (const __attribute__((address_space(1))) void*)(pa + kt_ + q * qstep),         \
            (__attribute__((address_space(3))) void*)((char*)lds + ab_ + q * 4096),        \
            16, 0, 0);                                                                     \
    _Pragma("unroll") for (int q = 0; q < 4; ++q)                                          \
        __builtin_amdgcn_global_load_lds(                                                  \
            (const __attribute__((address_space(1))) void*)(pb + kt_ + q * qstep),         \
            (__attribute__((address_space(3))) void*)((char*)lds + ab_ + 16384 + q * 4096),\
            16, 0, 0);                                                                     \
  } while (0)

  const int nt = K >> 6;
  STAGE(0, 0);
  STAGE(1, 1);
  asm volatile("s_waitcnt vmcnt(8)" ::: "memory");
  __builtin_amdgcn_s_barrier();

  for (int t = 0; t < nt; ++t) {
    const int buf = t & 1;
    const char* abase = (const char*)lds + buf * 32768;
    const char* bbase = abase + 16384;
    short8 af[4][2], bfr[4][2];
#pragma unroll
    for (int m = 0; m < 4; ++m)
#pragma unroll
      for (int ks = 0; ks < 2; ++ks)
        af[m][ks] = *reinterpret_cast<const short8*>(
            abase + (wr * 64 + m * 16 + ll) * 128 + (((ks * 4 + g) ^ swz) * 16));
#pragma unroll
    for (int n = 0; n < 4; ++n)
#pragma unroll
      for (int ks = 0; ks < 2; ++ks)
        bfr[n][ks] = *reinterpret_cast<const short8*>(
            bbase + (wc * 64 + n * 16 + ll) * 128 + (((ks * 4 + g) ^ swz) * 16));
    asm volatile("s_waitcnt lgkmcnt(0)" ::: "memory");
    __builtin_amdgcn_s_barrier();

    if (t < nt - 2) {
      STAGE(t + 2, buf);
      asm volatile("s_waitcnt vmcnt(8)" ::: "memory");
    } else if (t == nt - 2) {
      asm volatile("s_waitcnt vmcnt(0)" ::: "memory");
    }
    __builtin_amdgcn_sched_barrier(0);
    __builtin_amdgcn_s_setprio(1);
#pragma unroll
    for (int ks = 0; ks < 2; ++ks)
#pragma unroll
      for (int m = 0; m < 4; ++m)
#pragma unroll
        for (int n = 0; n < 4; ++n)
          acc[m][n] =
              __builtin_amdgcn_mfma_f32_16x16x32_bf16(af[m][ks], bfr[n][ks], acc[m][n], 0, 0, 0);
    __builtin_amdgcn_s_setprio(0);
    __builtin_amdgcn_s_barrier();
  }
#undef STAGE

#pragma unroll
  for (int m = 0; m < 4; ++m) {
#pragma unroll
    for (int n = 0; n < 4; ++n) {
      const int row = wr * 64 + m * 16 + g * 4;
      const int col = wc * 64 + n * 16 + ll;
      const float bias_v = bias[n0 + col];
#pragma unroll
      for (int r = 0; r < 4; ++r) {
        float val = acc[m][n][r] + bias_v;
        long off = (m0 + row + r) * (long)N + n0 + col;
        if constexpr (sizeof(OutT) == 2) {
          C[off] = (OutT)f2bf(val);
        } else {
          C[off] = val;
        }
      }
    }
  }
}

template <typename OutT>
__global__ __launch_bounds__(256) void gemm_p(const ushort* __restrict__ A,
                                              const ushort* __restrict__ B,
                                              const float* __restrict__ bias,
                                              OutT* __restrict__ C, int M, int N, int K) {
  gemm_body<OutT>(A, B, bias, C, M, N, K);
}

// K and V projections fused into one launch (blockIdx.z selects)
__global__ __launch_bounds__(256) void gemm_p_kv(const ushort* __restrict__ A,
                                                 const ushort* __restrict__ Bk,
                                                 const float* __restrict__ bk, float* Ck,
                                                 const ushort* __restrict__ Bv,
                                                 const float* __restrict__ bv, float* Cv,
                                                 int M, int N, int K) {
  if (blockIdx.z == 0)
    gemm_body<float>(A, Bk, bk, Ck, M, N, K);
  else
    gemm_body<float>(A, Bv, bv, Cv, M, N, K);
}

// ---------------- prep: build attn images once ----------------
// Per (bb,h): kimg = ushort[4][80][64] bf16, row j chunk-swizzled (t ^ (j&7));
//             vimg = f16[4][64][80] V^T with jb-block swizzle (jb ^ ((d>>2)&3)).

__global__ __launch_bounds__(256) void prep_kv(const float* __restrict__ k_f,
                                               const float* __restrict__ v_f,
                                               const float* __restrict__ bk,
                                               const float* __restrict__ bv,
                                               ushort* __restrict__ kimg,
                                               ushort* __restrict__ vimg) {
  __shared__ _Float16 vl[80][68];
  const int c = blockIdx.x, h = blockIdx.y, bb = blockIdx.z;
  const int tid = threadIdx.x;
  const long ibase = ((long)(bb * 24 + h)) * 20480 + c * 5120;

  for (int rr = tid; rr < 640; rr += 256) {
    int j = rr >> 3, t = rr & 7;
    short8 v = {};
    const float* src = nullptr;
    if (j < 77)
      src = k_f + ((long)((c * 2 + bb) * 77 + j)) * 1536 + h * 64 + t * 8;
    else if (j == 77)
      src = bk + h * 64 + t * 8;
    if (src) {
      float4 f0 = reinterpret_cast<const float4*>(src)[0];
      float4 f1 = reinterpret_cast<const float4*>(src)[1];
      v[0] = f2bf(f0.x); v[1] = f2bf(f0.y); v[2] = f2bf(f0.z); v[3] = f2bf(f0.w);
      v[4] = f2bf(f1.x); v[5] = f2bf(f1.y); v[6] = f2bf(f1.z); v[7] = f2bf(f1.w);
    }
    *reinterpret_cast<short8*>(kimg + ibase + j * 64 + (t ^ (j & 7)) * 8) = v;
  }
  for (int rr = tid; rr < 640; rr += 256) {
    int j = rr >> 3, t = rr & 7;
    half4 lo = {}, hi = {};
    const float* src = nullptr;
    if (j < 77)
      src = v_f + ((long)((c * 2 + bb) * 77 + j)) * 1536 + h * 64 + t * 8;
    else if (j == 77)
      src = bv + h * 64 + t * 8;
    if (src) {
      float4 f0 = reinterpret_cast<const float4*>(src)[0];
      float4 f1 = reinterpret_cast<const float4*>(src)[1];
      lo[0] = (_Float16)f0.x; lo[1] = (_Float16)f0.y; lo[2] = (_Float16)f0.z; lo[3] = (_Float16)f0.w;
      hi[0] = (_Float16)f1.x; hi[1] = (_Float16)f1.y; hi[2] = (_Float16)f1.z; hi[3] = (_Float16)f1.w;
    }
    *reinterpret_cast<half4*>(&vl[j][t * 8]) = lo;
    *reinterpret_cast<half4*>(&vl[j][t * 8 + 4]) = hi;
  }
  __syncthreads();
  const int d = tid & 63, jg = tid >> 6;
  ushort* vrow = vimg + ibase + d * 80;
  const int x = (d >> 2) & 3;
#pragma unroll
  for (int b = 0; b < 5; ++b) {
    int jb = jg * 5 + b;
    half4 hv;
#pragma unroll
    for (int e = 0; e < 4; ++e) hv[e] = vl[jb * 4 + e][d];
    *reinterpret_cast<half4*>(vrow + ((jb ^ x) << 2)) = hv;
  }
}

// ---------------- MFMA component-softmax attention (v4) ----------------
// grid (32 i-tiles, 24 heads, 2 bb), block 256 = 4 waves.
// V^T staged async into LDS (40 KB -> 3-4 blocks/CU); K-frags read DIRECTLY
// from L2-resident kimg (3.84 MB) with coalesced 16B/lane loads. Barrier only
// between QK/softmax and PV, so V staging hides under the QK phase.

__global__ __launch_bounds__(256) void attn_v4(const ushort* __restrict__ qg,
                                               const ushort* __restrict__ kimg,
                                               const ushort* __restrict__ vimg,
                                               ushort* __restrict__ ao) {
  __shared__ __align__(16) ushort vt[20480];   // 40 KB (f16 bits)
  const int tid = threadIdx.x;
  const int lane = tid & 63;
  const int w = tid >> 6;
  const int h = blockIdx.y, bb = blockIdx.z;
  const int i0 = blockIdx.x * 64;
  const long ib = ((long)(bb * 24 + h)) * 20480;

  // async V^T staging (consumed after the barrier below)
#pragma unroll
  for (int p = 0; p < 10; ++p) {
    int is = p * 4 + w;
    __builtin_amdgcn_global_load_lds(
        (const __attribute__((address_space(1))) void*)(vimg + ib + is * 512 + lane * 8),
        (__attribute__((address_space(3))) void*)((char*)vt + is * 1024), 16, 0, 0);
  }

  const int ll = lane & 15, g = lane >> 4;

  // ---- phase A: S^T[c] = K_c · Q_c^T, K-frags from global (L2) ----
  f32x4 s[4][5];
#pragma unroll
  for (int c = 0; c < 4; ++c)
#pragma unroll
    for (int m = 0; m < 5; ++m) s[c][m] = (f32x4){0.f, 0.f, 0.f, 0.f};

#pragma unroll
  for (int c = 0; c < 4; ++c) {
    const ushort* qbase =
        qg + ((long)((c * 2 + bb) * 2048 + i0 + w * 16 + ll)) * 1536 + h * 64 + g * 8;
    short8 qf0 = *reinterpret_cast<const short8*>(qbase);
    short8 qf1 = *reinterpret_cast<const short8*>(qbase + 32);
    const ushort* kbase = kimg + ib + c * 5120;
#pragma unroll
    for (int m = 0; m < 5; ++m) {
      const ushort* rb = kbase + (m * 16 + ll) * 64;
      short8 a0 = *reinterpret_cast<const short8*>(rb + (g ^ (ll & 7)) * 8);
      short8 a1 = *reinterpret_cast<const short8*>(rb + ((4 + g) ^ (ll & 7)) * 8);
      s[c][m] = __builtin_amdgcn_mfma_f32_16x16x32_bf16(a0, qf0, s[c][m], 0, 0, 0);
      s[c][m] = __builtin_amdgcn_mfma_f32_16x16x32_bf16(a1, qf1, s[c][m], 0, 0, 0);
    }
  }

  // ---- component softmax, fully per-lane ----
  const float scale = 0.125f;
  float wsum0 = 0.f, wsum1 = 0.f, wsum2 = 0.f, wsum3 = 0.f;
#pragma unroll
  for (int m = 0; m < 5; ++m) {
#pragma unroll
    for (int e = 0; e < 4; ++e) {
      float x0 = s[0][m][e] * scale, x1 = s[1][m][e] * scale;
      float x2 = s[2][m][e] * scale, x3 = s[3][m][e] * scale;
      float mx = fmaxf(fmaxf(x0, x1), fmaxf(x2, x3));
      float e0 = __expf(x0 - mx), e1 = __expf(x1 - mx);
      float e2 = __expf(x2 - mx), e3 = __expf(x3 - mx);
      float inv = __fdividef(1.f, e0 + e1 + e2 + e3);
      float w0 = e0 * inv, w1 = e1 * inv, w2 = e2 * inv, w3 = e3 * inv;
      int jj = m * 16 + g * 4 + e;
      float msk = (jj < 77) ? 1.f : 0.f;
      wsum0 += w0 * msk; wsum1 += w1 * msk; wsum2 += w2 * msk; wsum3 += w3 * msk;
      s[0][m][e] = w0; s[1][m][e] = w1; s[2][m][e] = w2; s[3][m][e] = w3;
    }
  }
  wsum0 += __shfl_xor(wsum0, 16); wsum0 += __shfl_xor(wsum0, 32);
  wsum1 += __shfl_xor(wsum1, 16); wsum1 += __shfl_xor(wsum1, 32);
  wsum2 += __shfl_xor(wsum2, 16); wsum2 += __shfl_xor(wsum2, 32);
  wsum3 += __shfl_xor(wsum3, 16); wsum3 += __shfl_xor(wsum3, 32);

  // patch pad row (j==77 lives at m=4, e=1, g==3) and zero rows 78,79
  const bool g3 = (g == 3);
  {
    float wsum[4] = {wsum0, wsum1, wsum2, wsum3};
#pragma unroll
    for (int c = 0; c < 4; ++c) {
      float w77 = s[c][4][1];
      float pwv = w77 * (4.0f / 77.0f) * (77.0f - wsum[c]);
      s[c][4][1] = g3 ? pwv : w77;
      s[c][4][2] = g3 ? 0.f : s[c][4][2];
      s[c][4][3] = g3 ? 0.f : s[c][4][3];
    }
  }

  // ---- weights -> f16 A-frags ----
  half4 wf[4][5];
#pragma unroll
  for (int c = 0; c < 4; ++c)
#pragma unroll
    for (int m = 0; m < 5; ++m) {
      half4 hv;
      hv[0] = (_Float16)s[c][m][0];
      hv[1] = (_Float16)s[c][m][1];
      hv[2] = (_Float16)s[c][m][2];
      hv[3] = (_Float16)s[c][m][3];
      wf[c][m] = hv;
    }

  __syncthreads();  // V^T staged (drains vmcnt) before PV reads it

  // ---- phase C: O_c = W_c · V_c  (V^T jb-swizzled in LDS) ----
  f32x4 o[4][4];
#pragma unroll
  for (int c = 0; c < 4; ++c)
#pragma unroll
    for (int n = 0; n < 4; ++n) o[c][n] = (f32x4){0.f, 0.f, 0.f, 0.f};

#pragma unroll
  for (int c = 0; c < 4; ++c)
#pragma unroll
    for (int m = 0; m < 5; ++m)
#pragma unroll
      for (int n = 0; n < 4; ++n) {
        const int dd = n * 16 + ll;
        const int jb = (m * 4 + g) ^ ((dd >> 2) & 3);
        half4 vf = *reinterpret_cast<const half4*>(
            reinterpret_cast<const _Float16*>(vt) + c * 5120 + dd * 80 + (jb << 2));
        o[c][n] = __builtin_amdgcn_mfma_f32_16x16x16f16(wf[c][m], vf, o[c][n], 0, 0, 0);
      }

  // ---- store: O row i = g*4+reg, col d = n*16+ll ----
#pragma unroll
  for (int c = 0; c < 4; ++c)
#pragma unroll
    for (int n = 0; n < 4; ++n)
#pragma unroll
      for (int r = 0; r < 4; ++r) {
        long row = (long)((c * 2 + bb) * 2048 + i0 + w * 16 + g * 4 + r);
        ao[row * 1536 + h * 64 + n * 16 + ll] = f2bf(o[c][n][r]);
      }
}

// ---------------- launcher ----------------

extern "C" void kernel_launch(void* const* d_in, const int* in_sizes, int n_in,
                              void* d_out, int out_size, void* d_ws, size_t ws_size,
                              hipStream_t stream) {
  (void)in_sizes; (void)n_in; (void)out_size; (void)ws_size;
  const float* hs  = (const float*)d_in[0];
  const float* ehs = (const float*)d_in[1];
  const float* Wq  = (const float*)d_in[2];
  const float* bq  = (const float*)d_in[3];
  const float* Wk  = (const float*)d_in[4];
  const float* bk  = (const float*)d_in[5];
  const float* Wv  = (const float*)d_in[6];
  const float* bv  = (const float*)d_in[7];
  const float* Wo  = (const float*)d_in[8];
  const float* bo  = (const float*)d_in[9];
  float* out = (float*)d_out;

  char* ws = (char*)d_ws;
  size_t off = 0;
  auto alloc = [&](size_t bytes) {
    char* p = ws + off;
    off += (bytes + 255) & ~(size_t)255;
    return p;
  };
  ushort* hs_bf  = (ushort*)alloc(16384UL * 1536 * 2);
  ushort* ehs_bf = (ushort*)alloc(640UL * 2048 * 2);
  ushort* Wq_bf  = (ushort*)alloc(1536UL * 1536 * 2);
  ushort* Wk_bf  = (ushort*)alloc(1536UL * 2048 * 2);
  ushort* Wv_bf  = (ushort*)alloc(1536UL * 2048 * 2);
  ushort* Wo_bf  = (ushort*)alloc(1536UL * 1536 * 2);
  ushort* q_bf   = (ushort*)alloc(16384UL * 1536 * 2);
  float*  k_f    = (float*)alloc(640UL * 1536 * 4);
  float*  v_f    = (float*)alloc(640UL * 1536 * 4);
  ushort* ao_bf  = (ushort*)alloc(16384UL * 1536 * 2);
  ushort* kimg   = (ushort*)alloc(48UL * 20480 * 2);
  ushort* vimg   = (ushort*)alloc(48UL * 20480 * 2);

  dim3 b256(256);
  cvt_all<<<4096, b256, 0, stream>>>(hs, hs_bf, Wq, Wq_bf, Wk, Wk_bf, Wv, Wv_bf,
                                     Wo, Wo_bf, ehs, ehs_bf);

  // K,V projections fused (M padded to 640; rows 616..639 bias-only, unused)
  gemm_p_kv<<<dim3(5, 12, 2), b256, 0, stream>>>(ehs_bf, Wk_bf, bk, k_f, Wv_bf, bv, v_f,
                                                 640, 1536, 2048);
  // build attn images
  prep_kv<<<dim3(4, 24, 2), b256, 0, stream>>>(k_f, v_f, bk, bv, kimg, vimg);
  // Q projection
  gemm_p<ushort><<<dim3(128, 12), b256, 0, stream>>>(hs_bf, Wq_bf, bq, q_bf, 16384, 1536, 1536);
  // MFMA component-softmax attention
  attn_v4<<<dim3(32, 24, 2), b256, 0, stream>>>(q_bf, kimg, vimg, ao_bf);
  // output projection -> d_out (f32)
  gemm_p<float><<<dim3(128, 12), b256, 0, stream>>>(ao_bf, Wo_bf, bo, out, 16384, 1536, 1536);
}

// Round 12
// 265.140 us; speedup vs baseline: 1.1100x; 1.0188x over previous
//
#include <hip/hip_runtime.h>
#include <hip/hip_bf16.h>

// Shapes (hardcoded from reference): C=4, B=2, BC=8, HEADS=24, DH=64, D=1536,
// CROSS=2048, S=2048, E=PAD=77. Output f32 [8,2048,1536].

typedef __attribute__((ext_vector_type(8))) short short8;
typedef __attribute__((ext_vector_type(4))) float f32x4;
typedef __attribute__((ext_vector_type(4))) _Float16 half4;

#define DEV __device__ __forceinline__

DEV ushort f2bf(float x) {
  __hip_bfloat16 h = __float2bfloat16(x);
  return *reinterpret_cast<ushort*>(&h);
}

// ---------------- merged conversion kernel ----------------

__global__ __launch_bounds__(256) void cvt_all(const float* __restrict__ hs, ushort* __restrict__ hs_bf,
                                               const float* __restrict__ Wq, ushort* __restrict__ Wq_bf,
                                               const float* __restrict__ Wk, ushort* __restrict__ Wk_bf,
                                               const float* __restrict__ Wv, ushort* __restrict__ Wv_bf,
                                               const float* __restrict__ Wo, ushort* __restrict__ Wo_bf,
                                               const float* __restrict__ ehs, ushort* __restrict__ ehs_bf) {
  const int b0 = 6291456;            // hs quads
  const int b1 = b0 + 589824;        // Wq
  const int b2 = b1 + 786432;        // Wk
  const int b3 = b2 + 786432;        // Wv
  const int b4 = b3 + 589824;        // Wo
  const int total = b4 + 327680;     // ehs (640*2048/4)
  int idx = blockIdx.x * blockDim.x + threadIdx.x;
  int stride = gridDim.x * blockDim.x;
  for (int q = idx; q < total; q += stride) {
    const float* in; ushort* out; int qq;
    bool zero = false;
    if (q < b0)      { in = hs;  out = hs_bf;  qq = q; }
    else if (q < b1) { in = Wq;  out = Wq_bf;  qq = q - b0; }
    else if (q < b2) { in = Wk;  out = Wk_bf;  qq = q - b1; }
    else if (q < b3) { in = Wv;  out = Wv_bf;  qq = q - b2; }
    else if (q < b4) { in = Wo;  out = Wo_bf;  qq = q - b3; }
    else {
      qq = q - b4;
      int r = qq >> 9;               // 512 quads per 2048-col row
      in = ehs; out = ehs_bf;
      zero = (r >= 616);
    }
    ushort4 o;
    if (!zero) {
      float4 f = reinterpret_cast<const float4*>(in)[qq];
      o.x = f2bf(f.x); o.y = f2bf(f.y); o.z = f2bf(f.z); o.w = f2bf(f.w);
    } else {
      o.x = 0; o.y = 0; o.z = 0; o.w = 0;
    }
    reinterpret_cast<ushort4*>(out)[qq] = o;
  }
}

// ---------------- deep-pipelined bf16 MFMA GEMM, 128^2 (round-3 proven) ----------
// C[m][n] = sum_k A[m][k]*B[n][k] + bias[n].  128x128 tile, BK=64, 4 waves (2x2).
// Double-buffered LDS (64 KB -> 2 blocks/CU). Raw s_barrier + counted vmcnt.
// T2 swizzle on LDS; NEW (r12): bijective XCD block swizzle (m204 formula),
// m-major decomposition -> each XCD holds its B panel L2-resident and streams
// a contiguous A slab. Pure index permutation; hazard protocol untouched.

template <typename OutT>
DEV void gemm_body(const ushort* __restrict__ A, const ushort* __restrict__ B,
                   const float* __restrict__ bias, OutT* __restrict__ C,
                   int M, int N, int K) {
  __shared__ __align__(16) ushort lds[32768];  // 2 bufs x (A 16KB | B 16KB)
  const int tid = threadIdx.x;
  const int lane = tid & 63;
  const int wid = tid >> 6;
  const int wr = wid >> 1, wc = wid & 1;

  // bijective XCD swizzle (handles nwg % 8 != 0), then m-major decomposition
  const int nwg = gridDim.x * gridDim.y;
  const int lin = blockIdx.y * gridDim.x + blockIdx.x;
  const int q8 = nwg >> 3, r8 = nwg & 7;
  const int xcd = lin & 7, i8 = lin >> 3;
  const int swl = (xcd < r8 ? xcd * (q8 + 1) : r8 * (q8 + 1) + (xcd - r8) * q8) + i8;
  const long m0 = (long)(swl / gridDim.y) * 128;
  const long n0 = (long)(swl % gridDim.y) * 128;

  const int ll = lane & 15, g = lane >> 4;
  const int swz = ll & 7;

  const int srow = wid * 8 + (lane >> 3);
  const int scol = ((lane & 7) ^ (lane >> 3)) * 8;
  const ushort* pa = A + (m0 + srow) * (long)K + scol;
  const ushort* pb = B + (n0 + srow) * (long)K + scol;
  const long qstep = 32 * (long)K;

  f32x4 acc[4][4] = {};

#define STAGE(tt, bsel)                                                                    \
  do {                                                                                     \
    const long kt_ = (long)(tt) * 64;                                                      \
    const int ab_ = (bsel) * 32768 + wid * 1024;                                           \
    _Pragma("unroll") for (int q = 0; q < 4; ++q)                                          \
        __builtin_amdgcn_global_load_lds(                                                  \
            (const __attribute__((address_space(1))) void*)(pa + kt_ + q * qstep),         \
            (__attribute__((address_space(3))) void*)((char*)lds + ab_ + q * 4096),        \
            16, 0, 0);                                                                     \
    _Pragma("unroll") for (int q = 0; q < 4; ++q)                                          \
        __builtin_amdgcn_global_load_lds(                                                  \
            (const __attribute__((address_space(1))) void*)(pb + kt_ + q * qstep),         \
            (__attribute__((address_space(3))) void*)((char*)lds + ab_ + 16384 + q * 4096),\
            16, 0, 0);                                                                     \
  } while (0)

  const int nt = K >> 6;
  STAGE(0, 0);
  STAGE(1, 1);
  asm volatile("s_waitcnt vmcnt(8)" ::: "memory");
  __builtin_amdgcn_s_barrier();

  for (int t = 0; t < nt; ++t) {
    const int buf = t & 1;
    const char* abase = (const char*)lds + buf * 32768;
    const char* bbase = abase + 16384;
    short8 af[4][2], bfr[4][2];
#pragma unroll
    for (int m = 0; m < 4; ++m)
#pragma unroll
      for (int ks = 0; ks < 2; ++ks)
        af[m][ks] = *reinterpret_cast<const short8*>(
            abase + (wr * 64 + m * 16 + ll) * 128 + (((ks * 4 + g) ^ swz) * 16));
#pragma unroll
    for (int n = 0; n < 4; ++n)
#pragma unroll
      for (int ks = 0; ks < 2; ++ks)
        bfr[n][ks] = *reinterpret_cast<const short8*>(
            bbase + (wc * 64 + n * 16 + ll) * 128 + (((ks * 4 + g) ^ swz) * 16));
    asm volatile("s_waitcnt lgkmcnt(0)" ::: "memory");
    __builtin_amdgcn_s_barrier();

    if (t < nt - 2) {
      STAGE(t + 2, buf);
      asm volatile("s_waitcnt vmcnt(8)" ::: "memory");
    } else if (t == nt - 2) {
      asm volatile("s_waitcnt vmcnt(0)" ::: "memory");
    }
    __builtin_amdgcn_sched_barrier(0);
    __builtin_amdgcn_s_setprio(1);
#pragma unroll
    for (int ks = 0; ks < 2; ++ks)
#pragma unroll
      for (int m = 0; m < 4; ++m)
#pragma unroll
        for (int n = 0; n < 4; ++n)
          acc[m][n] =
              __builtin_amdgcn_mfma_f32_16x16x32_bf16(af[m][ks], bfr[n][ks], acc[m][n], 0, 0, 0);
    __builtin_amdgcn_s_setprio(0);
    __builtin_amdgcn_s_barrier();
  }
#undef STAGE

#pragma unroll
  for (int m = 0; m < 4; ++m) {
#pragma unroll
    for (int n = 0; n < 4; ++n) {
      const int row = wr * 64 + m * 16 + g * 4;
      const int col = wc * 64 + n * 16 + ll;
      const float bias_v = bias[n0 + col];
#pragma unroll
      for (int r = 0; r < 4; ++r) {
        float val = acc[m][n][r] + bias_v;
        long off = (m0 + row + r) * (long)N + n0 + col;
        if constexpr (sizeof(OutT) == 2) {
          C[off] = (OutT)f2bf(val);
        } else {
          C[off] = val;
        }
      }
    }
  }
}

template <typename OutT>
__global__ __launch_bounds__(256) void gemm_p(const ushort* __restrict__ A,
                                              const ushort* __restrict__ B,
                                              const float* __restrict__ bias,
                                              OutT* __restrict__ C, int M, int N, int K) {
  gemm_body<OutT>(A, B, bias, C, M, N, K);
}

// K and V projections fused into one launch (blockIdx.z selects)
__global__ __launch_bounds__(256) void gemm_p_kv(const ushort* __restrict__ A,
                                                 const ushort* __restrict__ Bk,
                                                 const float* __restrict__ bk, float* Ck,
                                                 const ushort* __restrict__ Bv,
                                                 const float* __restrict__ bv, float* Cv,
                                                 int M, int N, int K) {
  if (blockIdx.z == 0)
    gemm_body<float>(A, Bk, bk, Ck, M, N, K);
  else
    gemm_body<float>(A, Bv, bv, Cv, M, N, K);
}

// ---------------- prep: build attn images once ----------------
// Per (bb,h): kimg = ushort[4][80][64] bf16, row j chunk-swizzled (t ^ (j&7));
//             vimg = f16[4][64][80] V^T with jb-block swizzle (jb ^ ((d>>2)&3)).

__global__ __launch_bounds__(256) void prep_kv(const float* __restrict__ k_f,
                                               const float* __restrict__ v_f,
                                               const float* __restrict__ bk,
                                               const float* __restrict__ bv,
                                               ushort* __restrict__ kimg,
                                               ushort* __restrict__ vimg) {
  __shared__ _Float16 vl[80][68];
  const int c = blockIdx.x, h = blockIdx.y, bb = blockIdx.z;
  const int tid = threadIdx.x;
  const long ibase = ((long)(bb * 24 + h)) * 20480 + c * 5120;

  for (int rr = tid; rr < 640; rr += 256) {
    int j = rr >> 3, t = rr & 7;
    short8 v = {};
    const float* src = nullptr;
    if (j < 77)
      src = k_f + ((long)((c * 2 + bb) * 77 + j)) * 1536 + h * 64 + t * 8;
    else if (j == 77)
      src = bk + h * 64 + t * 8;
    if (src) {
      float4 f0 = reinterpret_cast<const float4*>(src)[0];
      float4 f1 = reinterpret_cast<const float4*>(src)[1];
      v[0] = f2bf(f0.x); v[1] = f2bf(f0.y); v[2] = f2bf(f0.z); v[3] = f2bf(f0.w);
      v[4] = f2bf(f1.x); v[5] = f2bf(f1.y); v[6] = f2bf(f1.z); v[7] = f2bf(f1.w);
    }
    *reinterpret_cast<short8*>(kimg + ibase + j * 64 + (t ^ (j & 7)) * 8) = v;
  }
  for (int rr = tid; rr < 640; rr += 256) {
    int j = rr >> 3, t = rr & 7;
    half4 lo = {}, hi = {};
    const float* src = nullptr;
    if (j < 77)
      src = v_f + ((long)((c * 2 + bb) * 77 + j)) * 1536 + h * 64 + t * 8;
    else if (j == 77)
      src = bv + h * 64 + t * 8;
    if (src) {
      float4 f0 = reinterpret_cast<const float4*>(src)[0];
      float4 f1 = reinterpret_cast<const float4*>(src)[1];
      lo[0] = (_Float16)f0.x; lo[1] = (_Float16)f0.y; lo[2] = (_Float16)f0.z; lo[3] = (_Float16)f0.w;
      hi[0] = (_Float16)f1.x; hi[1] = (_Float16)f1.y; hi[2] = (_Float16)f1.z; hi[3] = (_Float16)f1.w;
    }
    *reinterpret_cast<half4*>(&vl[j][t * 8]) = lo;
    *reinterpret_cast<half4*>(&vl[j][t * 8 + 4]) = hi;
  }
  __syncthreads();
  const int d = tid & 63, jg = tid >> 6;
  ushort* vrow = vimg + ibase + d * 80;
  const int x = (d >> 2) & 3;
#pragma unroll
  for (int b = 0; b < 5; ++b) {
    int jb = jg * 5 + b;
    half4 hv;
#pragma unroll
    for (int e = 0; e < 4; ++e) hv[e] = vl[jb * 4 + e][d];
    *reinterpret_cast<half4*>(vrow + ((jb ^ x) << 2)) = hv;
  }
}

// ---------------- MFMA component-softmax attention (v4) ----------------
// grid (32 i-tiles, 24 heads, 2 bb), block 256 = 4 waves.
// V^T staged async into LDS (40 KB -> 3-4 blocks/CU); K-frags read DIRECTLY
// from L2-resident kimg (3.84 MB). Barrier only between QK/softmax and PV.

__global__ __launch_bounds__(256) void attn_v4(const ushort* __restrict__ qg,
                                               const ushort* __restrict__ kimg,
                                               const ushort* __restrict__ vimg,
                                               ushort* __restrict__ ao) {
  __shared__ __align__(16) ushort vt[20480];   // 40 KB (f16 bits)
  const int tid = threadIdx.x;
  const int lane = tid & 63;
  const int w = tid >> 6;
  const int h = blockIdx.y, bb = blockIdx.z;
  const int i0 = blockIdx.x * 64;
  const long ib = ((long)(bb * 24 + h)) * 20480;

#pragma unroll
  for (int p = 0; p < 10; ++p) {
    int is = p * 4 + w;
    __builtin_amdgcn_global_load_lds(
        (const __attribute__((address_space(1))) void*)(vimg + ib + is * 512 + lane * 8),
        (__attribute__((address_space(3))) void*)((char*)vt + is * 1024), 16, 0, 0);
  }

  const int ll = lane & 15, g = lane >> 4;

  f32x4 s[4][5];
#pragma unroll
  for (int c = 0; c < 4; ++c)
#pragma unroll
    for (int m = 0; m < 5; ++m) s[c][m] = (f32x4){0.f, 0.f, 0.f, 0.f};

#pragma unroll
  for (int c = 0; c < 4; ++c) {
    const ushort* qbase =
        qg + ((long)((c * 2 + bb) * 2048 + i0 + w * 16 + ll)) * 1536 + h * 64 + g * 8;
    short8 qf0 = *reinterpret_cast<const short8*>(qbase);
    short8 qf1 = *reinterpret_cast<const short8*>(qbase + 32);
    const ushort* kbase = kimg + ib + c * 5120;
#pragma unroll
    for (int m = 0; m < 5; ++m) {
      const ushort* rb = kbase + (m * 16 + ll) * 64;
      short8 a0 = *reinterpret_cast<const short8*>(rb + (g ^ (ll & 7)) * 8);
      short8 a1 = *reinterpret_cast<const short8*>(rb + ((4 + g) ^ (ll & 7)) * 8);
      s[c][m] = __builtin_amdgcn_mfma_f32_16x16x32_bf16(a0, qf0, s[c][m], 0, 0, 0);
      s[c][m] = __builtin_amdgcn_mfma_f32_16x16x32_bf16(a1, qf1, s[c][m], 0, 0, 0);
    }
  }

  const float scale = 0.125f;
  float wsum0 = 0.f, wsum1 = 0.f, wsum2 = 0.f, wsum3 = 0.f;
#pragma unroll
  for (int m = 0; m < 5; ++m) {
#pragma unroll
    for (int e = 0; e < 4; ++e) {
      float x0 = s[0][m][e] * scale, x1 = s[1][m][e] * scale;
      float x2 = s[2][m][e] * scale, x3 = s[3][m][e] * scale;
      float mx = fmaxf(fmaxf(x0, x1), fmaxf(x2, x3));
      float e0 = __expf(x0 - mx), e1 = __expf(x1 - mx);
      float e2 = __expf(x2 - mx), e3 = __expf(x3 - mx);
      float inv = __fdividef(1.f, e0 + e1 + e2 + e3);
      float w0 = e0 * inv, w1 = e1 * inv, w2 = e2 * inv, w3 = e3 * inv;
      int jj = m * 16 + g * 4 + e;
      float msk = (jj < 77) ? 1.f : 0.f;
      wsum0 += w0 * msk; wsum1 += w1 * msk; wsum2 += w2 * msk; wsum3 += w3 * msk;
      s[0][m][e] = w0; s[1][m][e] = w1; s[2][m][e] = w2; s[3][m][e] = w3;
    }
  }
  wsum0 += __shfl_xor(wsum0, 16); wsum0 += __shfl_xor(wsum0, 32);
  wsum1 += __shfl_xor(wsum1, 16); wsum1 += __shfl_xor(wsum1, 32);
  wsum2 += __shfl_xor(wsum2, 16); wsum2 += __shfl_xor(wsum2, 32);
  wsum3 += __shfl_xor(wsum3, 16); wsum3 += __shfl_xor(wsum3, 32);

  const bool g3 = (g == 3);
  {
    float wsum[4] = {wsum0, wsum1, wsum2, wsum3};
#pragma unroll
    for (int c = 0; c < 4; ++c) {
      float w77 = s[c][4][1];
      float pwv = w77 * (4.0f / 77.0f) * (77.0f - wsum[c]);
      s[c][4][1] = g3 ? pwv : w77;
      s[c][4][2] = g3 ? 0.f : s[c][4][2];
      s[c][4][3] = g3 ? 0.f : s[c][4][3];
    }
  }

  half4 wf[4][5];
#pragma unroll
  for (int c = 0; c < 4; ++c)
#pragma unroll
    for (int m = 0; m < 5; ++m) {
      half4 hv;
      hv[0] = (_Float16)s[c][m][0];
      hv[1] = (_Float16)s[c][m][1];
      hv[2] = (_Float16)s[c][m][2];
      hv[3] = (_Float16)s[c][m][3];
      wf[c][m] = hv;
    }

  __syncthreads();  // V^T staged (drains vmcnt) before PV reads it

  f32x4 o[4][4];
#pragma unroll
  for (int c = 0; c < 4; ++c)
#pragma unroll
    for (int n = 0; n < 4; ++n) o[c][n] = (f32x4){0.f, 0.f, 0.f, 0.f};

#pragma unroll
  for (int c = 0; c < 4; ++c)
#pragma unroll
    for (int m = 0; m < 5; ++m)
#pragma unroll
      for (int n = 0; n < 4; ++n) {
        const int dd = n * 16 + ll;
        const int jb = (m * 4 + g) ^ ((dd >> 2) & 3);
        half4 vf = *reinterpret_cast<const half4*>(
            reinterpret_cast<const _Float16*>(vt) + c * 5120 + dd * 80 + (jb << 2));
        o[c][n] = __builtin_amdgcn_mfma_f32_16x16x16f16(wf[c][m], vf, o[c][n], 0, 0, 0);
      }

#pragma unroll
  for (int c = 0; c < 4; ++c)
#pragma unroll
    for (int n = 0; n < 4; ++n)
#pragma unroll
      for (int r = 0; r < 4; ++r) {
        long row = (long)((c * 2 + bb) * 2048 + i0 + w * 16 + g * 4 + r);
        ao[row * 1536 + h * 64 + n * 16 + ll] = f2bf(o[c][n][r]);
      }
}

// ---------------- launcher ----------------

extern "C" void kernel_launch(void* const* d_in, const int* in_sizes, int n_in,
                              void* d_out, int out_size, void* d_ws, size_t ws_size,
                              hipStream_t stream) {
  (void)in_sizes; (void)n_in; (void)out_size; (void)ws_size;
  const float* hs  = (const float*)d_in[0];
  const float* ehs = (const float*)d_in[1];
  const float* Wq  = (const float*)d_in[2];
  const float* bq  = (const float*)d_in[3];
  const float* Wk  = (const float*)d_in[4];
  const float* bk  = (const float*)d_in[5];
  const float* Wv  = (const float*)d_in[6];
  const float* bv  = (const float*)d_in[7];
  const float* Wo  = (const float*)d_in[8];
  const float* bo  = (const float*)d_in[9];
  float* out = (float*)d_out;

  char* ws = (char*)d_ws;
  size_t off = 0;
  auto alloc = [&](size_t bytes) {
    char* p = ws + off;
    off += (bytes + 255) & ~(size_t)255;
    return p;
  };
  ushort* hs_bf  = (ushort*)alloc(16384UL * 1536 * 2);
  ushort* ehs_bf = (ushort*)alloc(640UL * 2048 * 2);
  ushort* Wq_bf  = (ushort*)alloc(1536UL * 1536 * 2);
  ushort* Wk_bf  = (ushort*)alloc(1536UL * 2048 * 2);
  ushort* Wv_bf  = (ushort*)alloc(1536UL * 2048 * 2);
  ushort* Wo_bf  = (ushort*)alloc(1536UL * 1536 * 2);
  ushort* q_bf   = (ushort*)alloc(16384UL * 1536 * 2);
  float*  k_f    = (float*)alloc(640UL * 1536 * 4);
  float*  v_f    = (float*)alloc(640UL * 1536 * 4);
  ushort* ao_bf  = (ushort*)alloc(16384UL * 1536 * 2);
  ushort* kimg   = (ushort*)alloc(48UL * 20480 * 2);
  ushort* vimg   = (ushort*)alloc(48UL * 20480 * 2);

  dim3 b256(256);
  cvt_all<<<4096, b256, 0, stream>>>(hs, hs_bf, Wq, Wq_bf, Wk, Wk_bf, Wv, Wv_bf,
                                     Wo, Wo_bf, ehs, ehs_bf);

  // K,V projections fused (M padded to 640; rows 616..639 bias-only, unused)
  gemm_p_kv<<<dim3(5, 12, 2), b256, 0, stream>>>(ehs_bf, Wk_bf, bk, k_f, Wv_bf, bv, v_f,
                                                 640, 1536, 2048);
  // build attn images
  prep_kv<<<dim3(4, 24, 2), b256, 0, stream>>>(k_f, v_f, bk, bv, kimg, vimg);
  // Q projection
  gemm_p<ushort><<<dim3(128, 12), b256, 0, stream>>>(hs_bf, Wq_bf, bq, q_bf, 16384, 1536, 1536);
  // MFMA component-softmax attention
  attn_v4<<<dim3(32, 24, 2), b256, 0, stream>>>(q_bf, kimg, vimg, ao_bf);
  // output projection -> d_out (f32)
  gemm_p<float><<<dim3(128, 12), b256, 0, stream>>>(ao_bf, Wo_bf, bo, out, 16384, 1536, 1536);
}